// Round 1
// 593.882 us; speedup vs baseline: 1.5251x; 1.5251x over previous
//
#include <hip/hip_runtime.h>

#define B_    8
#define CIN   32
#define COUT  32
#define H_    512
#define W_    512
#define SDIM  512

// 1/sqrt(512), 1/sqrt(32*3*3)
#define MOD_SCALE  0.044194173824159216f
#define CONV_SCALE 0.05892556509887896f

#define PXB 128           // pixels (w) per block
#define LW  130           // staged width = PXB + 2 halo

typedef unsigned short u16;
typedef __attribute__((ext_vector_type(8))) short           bf16x8;
typedef __attribute__((ext_vector_type(8))) unsigned short  ushort8;
typedef __attribute__((ext_vector_type(4))) float           f32x4;

__device__ __forceinline__ u16 f2bf(float x) {
    union { float f; unsigned u; } v; v.f = x;
    unsigned r = v.u + 0x7FFFu + ((v.u >> 16) & 1u);   // RNE
    return (u16)(r >> 16);
}
__device__ __forceinline__ float bf2f(u16 h) {
    union { float f; unsigned u; } v; v.u = ((unsigned)h) << 16;
    return v.f;
}

// ---------------------------------------------------------------------------
// Kernel 1: modulation + demodulation + split-bf16 weight export.
// One wave per (b, co). Outputs wh/wl in [b][tap(9)][co][ci] bf16 layout so a
// conv A-fragment (lane&15 = co-row, (lane>>4)*8 = ci-block) is one dwordx4.
// ---------------------------------------------------------------------------
__global__ __launch_bounds__(64) void modweights_kernel(
    const float* __restrict__ style,
    const float* __restrict__ weight,
    const float* __restrict__ mod_w,
    const float* __restrict__ mod_b,
    u16* __restrict__ wh,
    u16* __restrict__ wl)
{
    const int b  = blockIdx.x / COUT;
    const int co = blockIdx.x % COUT;
    const int t  = threadIdx.x;          // 0..63

    __shared__ float s_sh[CIN];

    // s[b][ci] = style[b] . mod_w[ci] * MOD_SCALE + mod_b[ci]
    // lane-parallel, coalesced float4 (old version: 512-iter serial scalar dot)
    const float4* st4 = (const float4*)(style + (size_t)b * SDIM);
    const float4 sv0 = st4[t];
    const float4 sv1 = st4[t + 64];

    for (int ci = 0; ci < CIN; ++ci) {
        const float4* mw4 = (const float4*)(mod_w + (size_t)ci * SDIM);
        const float4 a = mw4[t];
        const float4 c = mw4[t + 64];
        float p = sv0.x*a.x + sv0.y*a.y + sv0.z*a.z + sv0.w*a.w
                + sv1.x*c.x + sv1.y*c.y + sv1.z*c.z + sv1.w*c.w;
        #pragma unroll
        for (int off = 32; off > 0; off >>= 1) p += __shfl_xor(p, off);
        if (t == 0) s_sh[ci] = p * MOD_SCALE + mod_b[ci];
    }
    __syncthreads();

    const float* wco = weight + (size_t)co * CIN * 9;

    float ss = 0.f;
    for (int i = t; i < CIN * 9; i += 64) {
        const float v = CONV_SCALE * wco[i] * s_sh[i / 9];
        ss += v * v;
    }
    #pragma unroll
    for (int off = 32; off > 0; off >>= 1) ss += __shfl_xor(ss, off);
    const float dem = rsqrtf(ss + 1e-8f);

    for (int i = t; i < CIN * 9; i += 64) {
        const int ci  = i / 9;
        const int ofs = i - ci * 9;                 // kh*3+kw
        const float v = CONV_SCALE * wco[i] * s_sh[ci] * dem;
        const size_t o = (((size_t)b * 9 + ofs) * COUT + co) * CIN + ci;
        const u16 hb = f2bf(v);
        wh[o] = hb;
        wl[o] = f2bf(v - bf2f(hb));                 // residual: w ~= hi + lo
    }
}

// ---------------------------------------------------------------------------
// Kernel 2: implicit-GEMM conv on mfma_f32_16x16x32_bf16, 3-term bf16 split.
// Block = 256 thr (4 waves) = 32 co x 128 px x 1 output row.
//   wave (wm,wn): co-tile 16*wm, px-tile 64*wn; 4 px-subtiles of 16.
// x staged in LDS as [r(3)][w(130)][ci(32)] bf16 hi/lo, XOR-swizzled
// (idx ^= (w&7)<<3 in u16 units) -> conflict-free ds_read_b128 / write_b128.
// Per wave: 108 MFMA (9 taps x 4 sub x 3 split terms), 72 ds_read_b128.
// ---------------------------------------------------------------------------
__global__ __launch_bounds__(256) void conv_kernel(
    const float* __restrict__ x,
    const u16* __restrict__ wh,
    const u16* __restrict__ wl,
    float* __restrict__ out)
{
    __shared__ u16 xh[3 * LW * CIN];    // 24960 B
    __shared__ u16 xl[3 * LW * CIN];    // 24960 B

    const int t  = threadIdx.x;
    const int w0 = blockIdx.x * PXB;
    const int h  = blockIdx.y;
    const int b  = blockIdx.z;

    const int lane = t & 63;
    const int wid  = t >> 6;
    const int wm   = wid >> 1;          // co half: 0/1
    const int wn   = wid & 1;           // px half: 0/1
    const int l15  = lane & 15;
    const int k0   = (lane >> 4) * 8;   // ci-block of this lane

    // ---- A fragments: weights for all 9 taps, hi+lo, resident in VGPRs ----
    bf16x8 ah[9], al[9];
    #pragma unroll
    for (int ofs = 0; ofs < 9; ++ofs) {
        const size_t o = (((size_t)b * 9 + ofs) * COUT + wm * 16 + l15) * CIN + k0;
        ah[ofs] = *(const bf16x8*)(wh + o);
        al[ofs] = *(const bf16x8*)(wl + o);
    }

    // ---- stage x rows h-1..h+1, gw in [w0-1, w0+128], split to hi/lo ----
    // task = (r, cg, w): global loads coalesced along w; one ds_write_b128
    // per (hi,lo) packing 8 ci.
    for (int task = t; task < 3 * 4 * LW; task += 256) {
        const int w  = task % LW;
        const int rc = task / LW;       // 0..11
        const int r  = rc >> 2;
        const int cg = rc & 3;
        const int gw = w0 + w - 1;
        const int ih = h + r - 1;
        float v[8];
        if (ih >= 0 && ih < H_ && gw >= 0 && gw < W_) {
            const float* p = x + ((size_t)(b * CIN + cg * 8) * H_ + ih) * W_ + gw;
            #pragma unroll
            for (int j = 0; j < 8; ++j) v[j] = p[(size_t)j * H_ * W_];
        } else {
            #pragma unroll
            for (int j = 0; j < 8; ++j) v[j] = 0.f;
        }
        ushort8 hv, lv;
        #pragma unroll
        for (int j = 0; j < 8; ++j) {
            const u16 hb = f2bf(v[j]);
            hv[j] = hb;
            lv[j] = f2bf(v[j] - bf2f(hb));
        }
        const int idx = (((r * LW + w) * CIN) + cg * 8) ^ ((w & 7) << 3);
        *(ushort8*)(xh + idx) = hv;
        *(ushort8*)(xl + idx) = lv;
    }
    __syncthreads();

    // ---- main: D[co][px] += sum_tap W_tap[co][ci] * x[ci][px+tap] ----
    f32x4 acc[4];
    #pragma unroll
    for (int sub = 0; sub < 4; ++sub) acc[sub] = (f32x4){0.f, 0.f, 0.f, 0.f};

    #pragma unroll
    for (int ofs = 0; ofs < 9; ++ofs) {
        const int kh = ofs / 3;
        const int kw = ofs - kh * 3;
        #pragma unroll
        for (int sub = 0; sub < 4; ++sub) {
            const int wlp = wn * 64 + sub * 16 + l15 + kw;          // 0..129
            const int idx = (((kh * LW + wlp) * CIN) + k0) ^ ((wlp & 7) << 3);
            const bf16x8 bh = *(const bf16x8*)(xh + idx);
            const bf16x8 bl = *(const bf16x8*)(xl + idx);
            acc[sub] = __builtin_amdgcn_mfma_f32_16x16x32_bf16(ah[ofs], bh, acc[sub], 0, 0, 0);
            acc[sub] = __builtin_amdgcn_mfma_f32_16x16x32_bf16(ah[ofs], bl, acc[sub], 0, 0, 0);
            acc[sub] = __builtin_amdgcn_mfma_f32_16x16x32_bf16(al[ofs], bh, acc[sub], 0, 0, 0);
        }
    }

    // ---- epilogue: C/D layout col = lane&15 (px), row = (lane>>4)*4+j (co) ----
    #pragma unroll
    for (int sub = 0; sub < 4; ++sub) {
        const int opx = w0 + wn * 64 + sub * 16 + l15;
        #pragma unroll
        for (int j = 0; j < 4; ++j) {
            const int oco = wm * 16 + (lane >> 4) * 4 + j;
            out[(((size_t)b * COUT + oco) * H_ + h) * W_ + opx] = acc[sub][j];
        }
    }
}

// ---------------------------------------------------------------------------
extern "C" void kernel_launch(void* const* d_in, const int* in_sizes, int n_in,
                              void* d_out, int out_size, void* d_ws, size_t ws_size,
                              hipStream_t stream)
{
    const float* x      = (const float*)d_in[0];
    const float* style  = (const float*)d_in[1];
    const float* weight = (const float*)d_in[2];
    const float* mod_w  = (const float*)d_in[3];
    const float* mod_b  = (const float*)d_in[4];
    float* out = (float*)d_out;

    // ws: wh + wl, each B*9*COUT*CIN u16 = 147456 B (total 294912 B, same
    // footprint as the previous fp32 wmod buffer)
    u16* wh = (u16*)d_ws;
    u16* wl = wh + (size_t)B_ * 9 * COUT * CIN;

    modweights_kernel<<<B_ * COUT, 64, 0, stream>>>(style, weight, mod_w, mod_b, wh, wl);

    dim3 grid(W_ / PXB, H_, B_);
    conv_kernel<<<grid, 256, 0, stream>>>(x, wh, wl, out);
}

// Round 4
// 531.076 us; speedup vs baseline: 1.7055x; 1.1183x over previous
//
#include <hip/hip_runtime.h>

#define B_    8
#define CIN   32
#define COUT  32
#define H_    512
#define W_    512
#define SDIM  512

// 1/sqrt(512), 1/sqrt(32*3*3)
#define MOD_SCALE  0.044194173824159216f
#define CONV_SCALE 0.05892556509887896f

#define PXB 64            // pixels (w) per block
#define RB  4             // output rows per block
#define LR  6             // staged input rows = RB + 2
#define LW  66            // staged width = PXB + 2 halo

typedef unsigned short u16;
typedef __attribute__((ext_vector_type(8))) short           bf16x8;
typedef __attribute__((ext_vector_type(4))) float           f32x4;

__device__ __forceinline__ u16 f2bf(float x) {
    union { float f; unsigned u; } v; v.f = x;
    unsigned r = v.u + 0x7FFFu + ((v.u >> 16) & 1u);   // RNE
    return (u16)(r >> 16);
}
__device__ __forceinline__ float bf2f(u16 h) {
    union { float f; unsigned u; } v; v.u = ((unsigned)h) << 16;
    return v.f;
}

// ---------------------------------------------------------------------------
// Kernel 1: modulation + demodulation + split-bf16 weight export.
// (verbatim from round 1 — harness-verified)
// Layout: wh/wl [b][tap(9)][co][ci] so a conv A-fragment is one dwordx4.
// ---------------------------------------------------------------------------
__global__ __launch_bounds__(64) void modweights_kernel(
    const float* __restrict__ style,
    const float* __restrict__ weight,
    const float* __restrict__ mod_w,
    const float* __restrict__ mod_b,
    u16* __restrict__ wh,
    u16* __restrict__ wl)
{
    const int b  = blockIdx.x / COUT;
    const int co = blockIdx.x % COUT;
    const int t  = threadIdx.x;          // 0..63

    __shared__ float s_sh[CIN];

    const float4* st4 = (const float4*)(style + (size_t)b * SDIM);
    const float4 sv0 = st4[t];
    const float4 sv1 = st4[t + 64];

    for (int ci = 0; ci < CIN; ++ci) {
        const float4* mw4 = (const float4*)(mod_w + (size_t)ci * SDIM);
        const float4 a = mw4[t];
        const float4 c = mw4[t + 64];
        float p = sv0.x*a.x + sv0.y*a.y + sv0.z*a.z + sv0.w*a.w
                + sv1.x*c.x + sv1.y*c.y + sv1.z*c.z + sv1.w*c.w;
        #pragma unroll
        for (int off = 32; off > 0; off >>= 1) p += __shfl_xor(p, off);
        if (t == 0) s_sh[ci] = p * MOD_SCALE + mod_b[ci];
    }
    __syncthreads();

    const float* wco = weight + (size_t)co * CIN * 9;

    float ss = 0.f;
    for (int i = t; i < CIN * 9; i += 64) {
        const float v = CONV_SCALE * wco[i] * s_sh[i / 9];
        ss += v * v;
    }
    #pragma unroll
    for (int off = 32; off > 0; off >>= 1) ss += __shfl_xor(ss, off);
    const float dem = rsqrtf(ss + 1e-8f);

    for (int i = t; i < CIN * 9; i += 64) {
        const int ci  = i / 9;
        const int ofs = i - ci * 9;                 // kh*3+kw
        const float v = CONV_SCALE * wco[i] * s_sh[ci] * dem;
        const size_t o = (((size_t)b * 9 + ofs) * COUT + co) * CIN + ci;
        const u16 hb = f2bf(v);
        wh[o] = hb;
        wl[o] = f2bf(v - bf2f(hb));                 // residual: w ~= hi + lo
    }
}

// ---------------------------------------------------------------------------
// Kernel 2: implicit-GEMM conv, 4 output rows per block.
// Block = 256 thr (4 waves); tile = 32 co x 64 px x 4 rows.
//   wave (wm,wn): co-tile 16*wm, px-tile 32*wn (2 sub-fragments of 16 px).
// x staged once per block as [r(6)][w(66)][ci(32)] bf16 hi/lo, XOR-swizzled
// (u16 idx ^= (w&7)<<3) for conflict-free b128 access.
// Input rows streamed: each row's 3 kw-fragments loaded once from LDS,
// reused for all valid kh (up to 3 output rows) -> 72 ds_read_b128 and
// 216 MFMA per wave (ratio 3.0, was 1.5).
// NOTE round 4: reverted hip_bf16.h API + launch_bounds min-waves clause to
// round-1-verified forms (differential vs container failures in r2/r3).
// ---------------------------------------------------------------------------
__global__ __launch_bounds__(256) void conv_kernel(
    const float* __restrict__ x,
    const u16* __restrict__ wh,
    const u16* __restrict__ wl,
    float* __restrict__ out)
{
    __shared__ u16 xh[LR * LW * CIN];   // 25344 B
    __shared__ u16 xl[LR * LW * CIN];   // 25344 B

    const int t  = threadIdx.x;
    const int w0 = blockIdx.x * PXB;
    const int h0 = blockIdx.y * RB;
    const int b  = blockIdx.z;

    const int lane = t & 63;
    const int wid  = t >> 6;
    const int wm   = wid >> 1;          // co half
    const int wn   = wid & 1;           // px half
    const int l15  = lane & 15;
    const int k0   = (lane >> 4) * 8;   // ci-block of this lane

    // ---- A fragments: 9 taps hi/lo, coalesced dwordx4 loads ----
    bf16x8 ah[9], al[9];
    #pragma unroll
    for (int ofs = 0; ofs < 9; ++ofs) {
        const size_t o = (((size_t)b * 9 + ofs) * COUT + wm * 16 + l15) * CIN + k0;
        ah[ofs] = *(const bf16x8*)(wh + o);
        al[ofs] = *(const bf16x8*)(wl + o);
    }

    // ---- stage 6 input rows, split to bf16 hi/lo (manual RNE, r1-verified) ----
    for (int task = t; task < LR * 4 * LW; task += 256) {
        const int w  = task % LW;
        const int rc = task / LW;       // 0..23
        const int r  = rc >> 2;         // staged row 0..5 -> ih = h0+r-1
        const int cg = rc & 3;
        const int gw = w0 + w - 1;
        const int ih = h0 + r - 1;
        float v[8];
        if ((unsigned)ih < (unsigned)H_ && (unsigned)gw < (unsigned)W_) {
            const float* p = x + ((size_t)(b * CIN + cg * 8) * H_ + ih) * W_ + gw;
            #pragma unroll
            for (int j = 0; j < 8; ++j) v[j] = p[(size_t)j * H_ * W_];
        } else {
            #pragma unroll
            for (int j = 0; j < 8; ++j) v[j] = 0.f;
        }
        unsigned hu[4], lu[4];
        #pragma unroll
        for (int q = 0; q < 4; ++q) {
            const u16 h0b = f2bf(v[2*q]);
            const u16 h1b = f2bf(v[2*q+1]);
            const u16 l0b = f2bf(v[2*q]   - bf2f(h0b));
            const u16 l1b = f2bf(v[2*q+1] - bf2f(h1b));
            hu[q] = (unsigned)h0b | ((unsigned)h1b << 16);
            lu[q] = (unsigned)l0b | ((unsigned)l1b << 16);
        }
        const int idx = (((r * LW + w) * CIN) + cg * 8) ^ ((w & 7) << 3);  // 16B-aligned
        *(uint4*)(xh + idx) = make_uint4(hu[0], hu[1], hu[2], hu[3]);
        *(uint4*)(xl + idx) = make_uint4(lu[0], lu[1], lu[2], lu[3]);
    }
    __syncthreads();

    // ---- main: stream input rows; reuse kw-fragments across kh ----
    f32x4 acc[RB][2];
    #pragma unroll
    for (int r = 0; r < RB; ++r) {
        acc[r][0] = (f32x4){0.f, 0.f, 0.f, 0.f};
        acc[r][1] = (f32x4){0.f, 0.f, 0.f, 0.f};
    }

    #pragma unroll
    for (int r_in = 0; r_in < LR; ++r_in) {
        #pragma unroll
        for (int sub = 0; sub < 2; ++sub) {
            bf16x8 bh[3], bl[3];
            #pragma unroll
            for (int kw = 0; kw < 3; ++kw) {
                const int wl_ = wn * 32 + sub * 16 + l15 + kw;      // 0..65
                const int idx = (((r_in * LW + wl_) * CIN) + k0) ^ ((wl_ & 7) << 3);
                bh[kw] = *(const bf16x8*)(xh + idx);
                bl[kw] = *(const bf16x8*)(xl + idx);
            }
            #pragma unroll
            for (int kh = 0; kh < 3; ++kh) {
                const int r_out = r_in - kh;                        // compile-time
                if (r_out < 0 || r_out >= RB) continue;
                #pragma unroll
                for (int kw = 0; kw < 3; ++kw) {
                    const int tap = kh * 3 + kw;
                    acc[r_out][sub] = __builtin_amdgcn_mfma_f32_16x16x32_bf16(
                        ah[tap], bh[kw], acc[r_out][sub], 0, 0, 0);
                    acc[r_out][sub] = __builtin_amdgcn_mfma_f32_16x16x32_bf16(
                        ah[tap], bl[kw], acc[r_out][sub], 0, 0, 0);
                    acc[r_out][sub] = __builtin_amdgcn_mfma_f32_16x16x32_bf16(
                        al[tap], bh[kw], acc[r_out][sub], 0, 0, 0);
                }
            }
        }
    }

    // ---- epilogue: C/D layout col = lane&15 (px), row = (lane>>4)*4+j (co) ----
    #pragma unroll
    for (int r = 0; r < RB; ++r) {
        #pragma unroll
        for (int sub = 0; sub < 2; ++sub) {
            const int opx = w0 + wn * 32 + sub * 16 + l15;
            #pragma unroll
            for (int j = 0; j < 4; ++j) {
                const int oco = wm * 16 + (lane >> 4) * 4 + j;
                out[(((size_t)b * COUT + oco) * H_ + h0 + r) * W_ + opx] = acc[r][sub][j];
            }
        }
    }
}

// ---------------------------------------------------------------------------
extern "C" void kernel_launch(void* const* d_in, const int* in_sizes, int n_in,
                              void* d_out, int out_size, void* d_ws, size_t ws_size,
                              hipStream_t stream)
{
    const float* x      = (const float*)d_in[0];
    const float* style  = (const float*)d_in[1];
    const float* weight = (const float*)d_in[2];
    const float* mod_w  = (const float*)d_in[3];
    const float* mod_b  = (const float*)d_in[4];
    float* out = (float*)d_out;

    u16* wh = (u16*)d_ws;
    u16* wl = wh + (size_t)B_ * 9 * COUT * CIN;

    modweights_kernel<<<B_ * COUT, 64, 0, stream>>>(style, weight, mod_w, mod_b, wh, wl);

    dim3 grid(W_ / PXB, H_ / RB, B_);
    conv_kernel<<<grid, 256, 0, stream>>>(x, wh, wl, out);
}

// Round 5
// 494.553 us; speedup vs baseline: 1.8314x; 1.0738x over previous
//
#include <hip/hip_runtime.h>

#define B_    8
#define CIN   32
#define COUT  32
#define H_    512
#define W_    512
#define SDIM  512

// 1/sqrt(512), 1/sqrt(32*3*3)
#define MOD_SCALE  0.044194173824159216f
#define CONV_SCALE 0.05892556509887896f

#define PXB 64            // pixels (w) per block
#define RB  4             // output rows per block
#define LR  6             // staged input rows = RB + 2
#define LW  66            // staged width = PXB + 2 halo

typedef unsigned short u16;
typedef __attribute__((ext_vector_type(8))) _Float16        f16x8;
typedef __attribute__((ext_vector_type(4))) float           f32x4;

// ---------------------------------------------------------------------------
// Kernel 1: modulation + demodulation + fp16 weight export (single plane).
// Layout: w16 [b][tap(9)][co][ci] so a conv A-fragment is one dwordx4.
// fp32 math throughout; only the final store quantizes to fp16 (RNE).
// ---------------------------------------------------------------------------
__global__ __launch_bounds__(64) void modweights_kernel(
    const float* __restrict__ style,
    const float* __restrict__ weight,
    const float* __restrict__ mod_w,
    const float* __restrict__ mod_b,
    u16* __restrict__ w16)
{
    const int b  = blockIdx.x / COUT;
    const int co = blockIdx.x % COUT;
    const int t  = threadIdx.x;          // 0..63

    __shared__ float s_sh[CIN];

    const float4* st4 = (const float4*)(style + (size_t)b * SDIM);
    const float4 sv0 = st4[t];
    const float4 sv1 = st4[t + 64];

    for (int ci = 0; ci < CIN; ++ci) {
        const float4* mw4 = (const float4*)(mod_w + (size_t)ci * SDIM);
        const float4 a = mw4[t];
        const float4 c = mw4[t + 64];
        float p = sv0.x*a.x + sv0.y*a.y + sv0.z*a.z + sv0.w*a.w
                + sv1.x*c.x + sv1.y*c.y + sv1.z*c.z + sv1.w*c.w;
        #pragma unroll
        for (int off = 32; off > 0; off >>= 1) p += __shfl_xor(p, off);
        if (t == 0) s_sh[ci] = p * MOD_SCALE + mod_b[ci];
    }
    __syncthreads();

    const float* wco = weight + (size_t)co * CIN * 9;

    float ss = 0.f;
    for (int i = t; i < CIN * 9; i += 64) {
        const float v = CONV_SCALE * wco[i] * s_sh[i / 9];
        ss += v * v;
    }
    #pragma unroll
    for (int off = 32; off > 0; off >>= 1) ss += __shfl_xor(ss, off);
    const float dem = rsqrtf(ss + 1e-8f);

    for (int i = t; i < CIN * 9; i += 64) {
        const int ci  = i / 9;
        const int ofs = i - ci * 9;                 // kh*3+kw
        const float v = CONV_SCALE * wco[i] * s_sh[ci] * dem;
        const size_t o = (((size_t)b * 9 + ofs) * COUT + co) * CIN + ci;
        w16[o] = __builtin_bit_cast(u16, (_Float16)v);
    }
}

// ---------------------------------------------------------------------------
// Kernel 2: implicit-GEMM conv on mfma_f32_16x16x32_f16, single term.
// Block = 256 thr (4 waves); tile = 32 co x 64 px x 4 rows.
// x staged once per block as [r(6)][w(66)][ci(32)] fp16, XOR-swizzled
// (u16 idx ^= (w&7)<<3) for conflict-free b128 access. 25,344 B LDS
// -> 6 resident blocks/CU (was 3 with the bf16 hi/lo pair).
// Per wave: 36 ds_read_b128, 72 MFMA (1.0 MAC efficiency).
// XCD swizzle: each XCD owns one batch image (halo rows L2-local).
// ---------------------------------------------------------------------------
__global__ __launch_bounds__(256) void conv_kernel(
    const float* __restrict__ x,
    const u16* __restrict__ w16,
    float* __restrict__ out)
{
    __shared__ u16 xs[LR * LW * CIN];   // 25344 B

    // bijective XCD swizzle: flat 0..8191, swz = (flat%8)*1024 + flat/8
    // -> XCD k processes batch b = k; vertical halo neighbors co-resident.
    const int flat = blockIdx.x + (blockIdx.y << 3) + (blockIdx.z << 10);
    const int swz  = ((flat & 7) << 10) | (flat >> 3);
    const int bx   = swz & 7;
    const int by   = (swz >> 3) & 127;
    const int b    = swz >> 10;

    const int t  = threadIdx.x;
    const int w0 = bx * PXB;
    const int h0 = by * RB;

    const int lane = t & 63;
    const int wid  = t >> 6;
    const int wm   = wid >> 1;          // co half
    const int wn   = wid & 1;           // px half
    const int l15  = lane & 15;
    const int k0   = (lane >> 4) * 8;   // ci-block of this lane

    // ---- A fragments: 9 taps fp16, coalesced dwordx4 loads ----
    f16x8 af[9];
    #pragma unroll
    for (int ofs = 0; ofs < 9; ++ofs) {
        const size_t o = (((size_t)b * 9 + ofs) * COUT + wm * 16 + l15) * CIN + k0;
        af[ofs] = *(const f16x8*)(w16 + o);
    }

    // ---- stage 6 input rows, fp32 -> fp16 (RNE via _Float16 cast) ----
    for (int task = t; task < LR * 4 * LW; task += 256) {
        const int w  = task % LW;
        const int rc = task / LW;       // 0..23
        const int r  = rc >> 2;         // staged row 0..5 -> ih = h0+r-1
        const int cg = rc & 3;
        const int gw = w0 + w - 1;
        const int ih = h0 + r - 1;
        float v[8];
        if ((unsigned)ih < (unsigned)H_ && (unsigned)gw < (unsigned)W_) {
            const float* p = x + ((size_t)(b * CIN + cg * 8) * H_ + ih) * W_ + gw;
            #pragma unroll
            for (int j = 0; j < 8; ++j) v[j] = p[(size_t)j * H_ * W_];
        } else {
            #pragma unroll
            for (int j = 0; j < 8; ++j) v[j] = 0.f;
        }
        unsigned hu[4];
        #pragma unroll
        for (int q = 0; q < 4; ++q) {
            const u16 a = __builtin_bit_cast(u16, (_Float16)v[2*q]);
            const u16 c = __builtin_bit_cast(u16, (_Float16)v[2*q+1]);
            hu[q] = (unsigned)a | ((unsigned)c << 16);
        }
        const int idx = (((r * LW + w) * CIN) + cg * 8) ^ ((w & 7) << 3);  // 16B-aligned
        *(uint4*)(xs + idx) = make_uint4(hu[0], hu[1], hu[2], hu[3]);
    }
    __syncthreads();

    // ---- main: stream input rows; reuse kw-fragments across kh ----
    f32x4 acc[RB][2];
    #pragma unroll
    for (int r = 0; r < RB; ++r) {
        acc[r][0] = (f32x4){0.f, 0.f, 0.f, 0.f};
        acc[r][1] = (f32x4){0.f, 0.f, 0.f, 0.f};
    }

    #pragma unroll
    for (int r_in = 0; r_in < LR; ++r_in) {
        #pragma unroll
        for (int sub = 0; sub < 2; ++sub) {
            f16x8 bf[3];
            #pragma unroll
            for (int kw = 0; kw < 3; ++kw) {
                const int wl_ = wn * 32 + sub * 16 + l15 + kw;      // 0..65
                const int idx = (((r_in * LW + wl_) * CIN) + k0) ^ ((wl_ & 7) << 3);
                bf[kw] = *(const f16x8*)(xs + idx);
            }
            #pragma unroll
            for (int kh = 0; kh < 3; ++kh) {
                const int r_out = r_in - kh;                        // compile-time
                if (r_out < 0 || r_out >= RB) continue;
                #pragma unroll
                for (int kw = 0; kw < 3; ++kw) {
                    acc[r_out][sub] = __builtin_amdgcn_mfma_f32_16x16x32_f16(
                        af[kh * 3 + kw], bf[kw], acc[r_out][sub], 0, 0, 0);
                }
            }
        }
    }

    // ---- epilogue: C/D layout col = lane&15 (px), row = (lane>>4)*4+j (co) ----
    #pragma unroll
    for (int r = 0; r < RB; ++r) {
        #pragma unroll
        for (int sub = 0; sub < 2; ++sub) {
            const int opx = w0 + wn * 32 + sub * 16 + l15;
            #pragma unroll
            for (int j = 0; j < 4; ++j) {
                const int oco = wm * 16 + (lane >> 4) * 4 + j;
                out[(((size_t)b * COUT + oco) * H_ + h0 + r) * W_ + opx] = acc[r][sub][j];
            }
        }
    }
}

// ---------------------------------------------------------------------------
extern "C" void kernel_launch(void* const* d_in, const int* in_sizes, int n_in,
                              void* d_out, int out_size, void* d_ws, size_t ws_size,
                              hipStream_t stream)
{
    const float* x      = (const float*)d_in[0];
    const float* style  = (const float*)d_in[1];
    const float* weight = (const float*)d_in[2];
    const float* mod_w  = (const float*)d_in[3];
    const float* mod_b  = (const float*)d_in[4];
    float* out = (float*)d_out;

    u16* w16 = (u16*)d_ws;   // B*9*COUT*CIN u16 = 147,456 B

    modweights_kernel<<<B_ * COUT, 64, 0, stream>>>(style, weight, mod_w, mod_b, w16);

    dim3 grid(W_ / PXB, H_ / RB, B_);
    conv_kernel<<<grid, 256, 0, stream>>>(x, w16, out);
}